// Round 19
// baseline (144.090 us; speedup 1.0000x reference)
//
#include <hip/hip_runtime.h>
#include <hip/hip_bf16.h>
#include <stdint.h>

#define B_ 8
#define N_ 2048
#define F_ 128
#define D_ 128

typedef short bf16x8 __attribute__((ext_vector_type(8)));
typedef float f32x4 __attribute__((ext_vector_type(4)));

__device__ __forceinline__ unsigned short f2bf(float f) {
    unsigned u = __float_as_uint(f);
    u += 0x7fffu + ((u >> 16) & 1u);
    return (unsigned short)(u >> 16);
}

// ---------------- Kernel 1 (tiny): W[f][d] fp32 -> Wt[d][f] bf16 (proven body) ----------------
__global__ __launch_bounds__(256) void k_wt(const float* __restrict__ W,
                                            unsigned short* __restrict__ Wt) {
    int c = blockIdx.x * 256 + threadIdx.x;
    int d = c >> 4, f0 = (c & 15) * 8;
    union { bf16x8 v; unsigned short u[8]; } pk;
#pragma unroll
    for (int e = 0; e < 8; ++e) pk.u[e] = f2bf(W[(size_t)(f0 + e) * D_ + d]);
    *(bf16x8*)(Wt + (size_t)d * F_ + f0) = pk.v;
}

// ---------------- Kernel 2: FUSED deg -> feat -> flag -> GEMM ----------------
// 512 blocks x 256 thr (4 waves). Block (b = bid&7, slab = bid>>3) owns 32 rows R0=slab*32.
// Phase D: rowsums of own 32 adj rows -> rsS (LDS only).
// Phase F: gt[b][d][own m] = rs[m]*(X@W + bias)^T  (proven k_feat body, 32-row variant).
// Flag: threadfence + release; spin on own batch's 64 flags.
// Phase G: out = relu(rs[n] * adj @ gt^T), BM=32 BN=128 BK=64, R9-proven counted-vmcnt skeleton.
#define GBUF 20480            // per GEMM buffer: A 4 KB + B 16 KB
#define VM(n) asm volatile("s_waitcnt vmcnt(" #n ")" ::: "memory")
#define LGKM0 asm volatile("s_waitcnt lgkmcnt(0)" ::: "memory")
#define SCHED __builtin_amdgcn_sched_barrier(0)
#define BAR __builtin_amdgcn_s_barrier()

__global__ __launch_bounds__(256) void k_fused(const float* __restrict__ adj,
                                               const float* __restrict__ x,
                                               const unsigned short* __restrict__ Wt,
                                               const float* __restrict__ bias,
                                               unsigned short* __restrict__ gt,
                                               unsigned int* __restrict__ flags,
                                               float* __restrict__ out) {
    __shared__ __align__(16) unsigned char lds[2 * GBUF];   // 40 KB (feat overlay: sX 8K + sW 32K)
    __shared__ float rsS[32];

    const int bid = blockIdx.x;
    const int b = bid & 7;
    const int slab = bid >> 3;          // 0..63
    const int R0 = slab * 32;

    const float* adjB = adj + (size_t)(b * N_ + R0) * N_;
    const unsigned short* gtB = gt + (size_t)b * D_ * N_;

    const int t = threadIdx.x;
    const int w = t >> 6, l = t & 63, lr = l & 15, lh = l >> 4;

    // =============== Phase D: rowsums (4 waves x 8 rows) ===============
#pragma unroll 2
    for (int rr = 0; rr < 8; ++rr) {
        const float4* p = (const float4*)(adjB + (size_t)(w * 8 + rr) * N_);
        float s = 0.f;
#pragma unroll
        for (int j = 0; j < 8; ++j) {
            float4 v = p[j * 64 + l];
            s += (v.x + v.y) + (v.z + v.w);
        }
#pragma unroll
        for (int m = 1; m < 64; m <<= 1) s += __shfl_xor(s, m, 64);
        if (l == 0) rsS[w * 8 + rr] = (s > 0.f) ? (1.0f / sqrtf(s)) : 0.f;
    }
    __syncthreads();

    // =============== Phase F: feat (proven k_feat body, 32 rows) ===============
    {
        unsigned char* sX = lds;              // 32 x 256 B = 8 KB
        unsigned char* sW = lds + 8192;       // 128 x 256 B = 32 KB
        // stage sW from Wt via DMA (proven: linear dest + inverse-swizzled source)
#pragma unroll
        for (int j = 0; j < 8; ++j) {
            int c = j * 256 + t;
            unsigned L = (unsigned)c * 16u;
            unsigned lg = L ^ (((L >> 8) & 7u) << 4);
            __builtin_amdgcn_global_load_lds(
                (const __attribute__((address_space(1))) void*)((const unsigned char*)Wt + lg),
                (__attribute__((address_space(3))) void*)(sW + L), 16, 0, 0);
        }
        // stage sX rows R0..R0+31 of x[b] (proven reg-staged pattern)
#pragma unroll
        for (int j = 0; j < 2; ++j) {
            int c = j * 256 + t;
            int row = c >> 4, sub = c & 15;
            const float4* src = (const float4*)(x + (size_t)(b * N_ + R0 + row) * F_ + sub * 8);
            float4 v0 = src[0], v1 = src[1];
            union { bf16x8 v; unsigned short u[8]; } pk;
            pk.u[0] = f2bf(v0.x); pk.u[1] = f2bf(v0.y); pk.u[2] = f2bf(v0.z); pk.u[3] = f2bf(v0.w);
            pk.u[4] = f2bf(v1.x); pk.u[5] = f2bf(v1.y); pk.u[6] = f2bf(v1.z); pk.u[7] = f2bf(v1.w);
            unsigned byte = (unsigned)(row * 256 + sub * 16);
            byte ^= ((byte >> 8) & 7u) << 4;
            *(bf16x8*)(sX + byte) = pk.v;
        }
        __syncthreads();

        const int rw = w & 1, ch = w >> 1;    // rows rw*16, cols ch*64
        f32x4 acc4[4];
#pragma unroll
        for (int j = 0; j < 4; ++j) acc4[j] = (f32x4){0.f, 0.f, 0.f, 0.f};
#pragma unroll
        for (int ks = 0; ks < 4; ++ks) {
            unsigned abyte = (unsigned)((rw * 16 + lr) * 256 + lh * 16 + ks * 64);
            abyte ^= ((abyte >> 8) & 7u) << 4;
            bf16x8 a = *(const bf16x8*)(sX + abyte);
#pragma unroll
            for (int j = 0; j < 4; ++j) {
                int d = ch * 64 + j * 16 + lr;
                unsigned bbyte = (unsigned)(d * 256 + lh * 16 + ks * 64);
                bbyte ^= ((bbyte >> 8) & 7u) << 4;
                bf16x8 bb = *(const bf16x8*)(sW + bbyte);
                acc4[j] = __builtin_amdgcn_mfma_f32_16x16x32_bf16(a, bb, acc4[j], 0, 0, 0);
            }
        }
        const int mloc = rw * 16 + lh * 4;
        float4 r4 = *(const float4*)(rsS + mloc);
        float rr4[4] = {r4.x, r4.y, r4.z, r4.w};
#pragma unroll
        for (int j = 0; j < 4; ++j) {
            int d = ch * 64 + j * 16 + lr;
            float bv = bias[d];
#pragma unroll
            for (int r = 0; r < 4; ++r)
                gt[((size_t)b * D_ + d) * N_ + R0 + mloc + r] = f2bf((acc4[j][r] + bv) * rr4[r]);
        }
    }

    // =============== Flag: publish own gt slab; wait for batch ===============
    __threadfence();                 // each thread: own gt stores device-visible
    __syncthreads();
    if (t == 0)
        __hip_atomic_store(&flags[b * 64 + slab], 1u, __ATOMIC_RELEASE, __HIP_MEMORY_SCOPE_AGENT);
    if (t < 64) {
        while (__hip_atomic_load(&flags[b * 64 + t], __ATOMIC_ACQUIRE, __HIP_MEMORY_SCOPE_AGENT) == 0u)
            __builtin_amdgcn_s_sleep(2);
    }
    __syncthreads();

    // =============== Phase G: GEMM (R9-proven skeleton) ===============
    // A: thread owns row t>>3 (0..31), 8 fp32 at col (t&7)*8 per 64-wide K-slice
    const float* aSrc = adjB + (size_t)(t >> 3) * N_ + (t & 7) * 8;
    const unsigned aRow = (unsigned)(t >> 3);
    unsigned aL = aRow * 128u + (unsigned)((t & 7) * 16);
    aL ^= ((aRow & 7u) << 4) ^ ((aRow & 8u) << 3);

    // B: 4 chunks/thread; linear LDS dest (DMA), inverse-swizzled global src
    const unsigned short* bSrc[4];
    unsigned bL[4];
#pragma unroll
    for (int i = 0; i < 4; ++i) {
        unsigned L = (unsigned)(i * 256 + t) * 16u;          // 0..16383
        unsigned d0 = L >> 7;                                // 0..127
        unsigned w0 = (L & 127u) ^ ((d0 & 7u) << 4) ^ ((d0 & 8u) << 3);
        bSrc[i] = gtB + (size_t)d0 * N_ + (w0 >> 1);
        bL[i] = L;
    }

    auto issueB = [&](int buf, int J) {
        unsigned char* pB = lds + buf * GBUF + 4096;
#pragma unroll
        for (int i = 0; i < 4; ++i) {
            __builtin_amdgcn_global_load_lds(
                (const __attribute__((address_space(1))) void*)(bSrc[i] + J * 64),
                (__attribute__((address_space(3))) void*)(pB + bL[i]), 16, 0, 0);
        }
    };
    auto cvtW = [&](int buf, const f32x4& x0, const f32x4& x1) {
        unsigned u0, u1, u2, u3;
        asm("v_cvt_pk_bf16_f32 %0, %1, %2" : "=v"(u0) : "v"(x0[0]), "v"(x0[1]));
        asm("v_cvt_pk_bf16_f32 %0, %1, %2" : "=v"(u1) : "v"(x0[2]), "v"(x0[3]));
        asm("v_cvt_pk_bf16_f32 %0, %1, %2" : "=v"(u2) : "v"(x1[0]), "v"(x1[1]));
        asm("v_cvt_pk_bf16_f32 %0, %1, %2" : "=v"(u3) : "v"(x1[2]), "v"(x1[3]));
        union { unsigned uu[4]; bf16x8 v; } pk;
        pk.uu[0] = u0; pk.uu[1] = u1; pk.uu[2] = u2; pk.uu[3] = u3;
        *(bf16x8*)(lds + buf * GBUF + aL) = pk.v;
    };

    f32x4 acc[2][2];
#pragma unroll
    for (int i = 0; i < 2; ++i)
#pragma unroll
        for (int jn = 0; jn < 2; ++jn) acc[i][jn] = (f32x4){0.f, 0.f, 0.f, 0.f};

    const int NITER = N_ / 64;   // 32

    // prologue: B0 DMA [4]; A0 regs [2]; A1 regs [2]; land B0+A0; cvt A0 -> buf0
    issueB(0, 0); SCHED;
    f32x4 aC0 = *(const f32x4*)(aSrc);
    f32x4 aC1 = *(const f32x4*)(aSrc + 4);
    SCHED;
    f32x4 aN0 = *(const f32x4*)(aSrc + 64);
    f32x4 aN1 = *(const f32x4*)(aSrc + 68);
    SCHED;
    VM(2); SCHED;
    cvtW(0, aC0, aC1);
    LGKM0; SCHED;
    aC0 = aN0; aC1 = aN1;        // aC = A(1)

    for (int it = 0; it < NITER; ++it) {
        const int cur = it & 1, nxt = cur ^ 1;
        if (it + 1 < NITER) { issueB(nxt, it + 1); }
        SCHED;
        if (it + 2 < NITER) {
            const float* s = aSrc + (it + 2) * 64;
            aN0 = *(const f32x4*)(s);
            aN1 = *(const f32x4*)(s + 4);
        }
        SCHED;
        if (it < NITER - 2)      VM(6);
        else if (it == NITER - 2) VM(4);
        else                      VM(0);
        SCHED; BAR;

        // MFMA over buf cur
        {
            const unsigned char* pA = lds + cur * GBUF;
            const unsigned char* pB = pA + 4096;
#pragma unroll
            for (int kk = 0; kk < 2; ++kk) {
                const unsigned kgoff = (unsigned)(kk * 64 + lh * 16);
                bf16x8 a_[2], b_[2];
#pragma unroll
                for (int i = 0; i < 2; ++i) {
                    unsigned row = (unsigned)(i * 16 + lr);
                    unsigned byte = row * 128u + kgoff;
                    byte ^= ((row & 7u) << 4) ^ ((row & 8u) << 3);
                    a_[i] = *(const bf16x8*)(pA + byte);
                }
#pragma unroll
                for (int jn = 0; jn < 2; ++jn) {
                    unsigned d = (unsigned)(w * 32 + jn * 16 + lr);
                    unsigned byte = d * 128u + kgoff;
                    byte ^= ((d & 7u) << 4) ^ ((d & 8u) << 3);
                    b_[jn] = *(const bf16x8*)(pB + byte);
                }
#pragma unroll
                for (int i = 0; i < 2; ++i)
#pragma unroll
                    for (int jn = 0; jn < 2; ++jn)
                        acc[i][jn] = __builtin_amdgcn_mfma_f32_16x16x32_bf16(
                            a_[i], b_[jn], acc[i][jn], 0, 0, 0);
            }
        }
        if (it + 1 < NITER) {
            cvtW(nxt, aC0, aC1);
            aC0 = aN0; aC1 = aN1;
        }
        LGKM0; SCHED; BAR;
    }

    // epilogue: rs[n] (LDS) * acc, relu, store
#pragma unroll
    for (int i = 0; i < 2; ++i) {
#pragma unroll
        for (int r = 0; r < 4; ++r) {
            int rowl = i * 16 + lh * 4 + r;
            float rsn = rsS[rowl];
#pragma unroll
            for (int jn = 0; jn < 2; ++jn) {
                int d = w * 32 + jn * 16 + lr;
                float v = acc[i][jn][r] * rsn;
                out[((size_t)(b * N_ + R0 + rowl)) * D_ + d] = fmaxf(v, 0.f);
            }
        }
    }
}

extern "C" void kernel_launch(void* const* d_in, const int* in_sizes, int n_in,
                              void* d_out, int out_size, void* d_ws, size_t ws_size,
                              hipStream_t stream) {
    const float* inputs = (const float*)d_in[0];   // [B,N,F]
    const float* adj    = (const float*)d_in[1];   // [B,N,N]
    const float* Wk     = (const float*)d_in[2];   // [F,D]
    const float* Wb     = (const float*)d_in[3];   // [D]
    float* out = (float*)d_out;

    char* ws = (char*)d_ws;
    unsigned short* gt   = (unsigned short*)(ws + (1 << 20));   // 4 MB  @ 1 MB
    unsigned short* Wt   = (unsigned short*)(ws + (6 << 20));   // 32 KB @ 6 MB
    unsigned int* flags  = (unsigned int*)(ws + (8 << 20));     // 2 KB  @ 8 MB

    hipMemsetAsync(flags, 0, 512 * sizeof(unsigned int), stream);
    k_wt   <<<8, 256, 0, stream>>>(Wk, Wt);
    k_fused<<<512, 256, 0, stream>>>(adj, inputs, Wt, Wb, gt, flags, out);
}